// Round 2
// baseline (230.742 us; speedup 1.0000x reference)
//
#include <hip/hip_runtime.h>

// WindowSlice: B=64, T=4096, C=128 fp32. L = ceil(0.9*T) = 3687.
// out[b,i,c] = lerp(x[b, starts[b]+lo(i), c], x[b, starts[b]+lo(i)+1, c], w(i))
// where t = clip(i * L/(T-1), 0, L-1), lo = min(floor(t), L-2), w = t - lo.
//
// v2.1 (compile fix of v2): __builtin_nontemporal_store needs a clang native
// vector type, not HIP_vector_type. Use ext_vector_type(4) float for the store.
//
// v2 rationale (memory-bound, ~244 MiB unique HBM traffic, roofline ~40 µs):
//  - 2 output rows per thread: 4 independent 16B loads in flight.
//  - block-uniform b -> starts[b] becomes a scalar s_load.
//  - bijective XCD-chunked swizzle (NBLK % 8 == 0) for input-row reuse in L2.
//  - nontemporal stores: output is write-once/never-read; keep the write
//    stream from evicting the input stream out of L2/L3 before its reuse.

constexpr int B_ = 64;
constexpr int T_ = 4096;
constexpr int C_ = 128;
constexpr int L_ = 3687;            // ceil(0.9 * 4096)
constexpr int C4 = C_ / 4;          // 32 float4 per row
constexpr int ROWS_PER_BLOCK = 16;  // 256 threads = 32 c4-lanes x 8 row-slots x 2 rows
constexpr int NBLK = B_ * T_ / ROWS_PER_BLOCK;       // 16384 (divisible by 8)
constexpr int BLOCKS_PER_B = T_ / ROWS_PER_BLOCK;    // 256
constexpr int NXCD = 8;

typedef float f32x4 __attribute__((ext_vector_type(4)));

__global__ __launch_bounds__(256, 8)
void WindowSlice_kernel(const float4* __restrict__ x,
                        const int*    __restrict__ starts,
                        float4*       __restrict__ out) {
    // Bijective XCD swizzle: each XCD gets a contiguous chunk of 2048 blocks
    // (= 8 consecutive samples' worth of rows). NBLK % NXCD == 0 -> bijective.
    const int bid = blockIdx.x;
    const int swz = (bid & (NXCD - 1)) * (NBLK / NXCD) + (bid >> 3);

    const int b  = swz >> 8;                          // / BLOCKS_PER_B (uniform)
    const int i0 = (swz & (BLOCKS_PER_B - 1)) * ROWS_PER_BLOCK;
    const int c4 = threadIdx.x & 31;
    const int rr = threadIdx.x >> 5;                  // 0..7

    const int start = starts[b];                      // block-uniform -> s_load

    const double step = (double)L_ / (double)(T_ - 1);

    const int i_a = i0 + rr;        // rows rr and rr+8 of this block's 16
    const int i_b = i_a + 8;

    // --- interp coordinates (double for exact lo/w, negligible VALU) ---
    double ta = (double)i_a * step;
    if (ta > (double)(L_ - 1)) ta = (double)(L_ - 1);
    int lo_a = (int)ta;
    if (lo_a > L_ - 2) lo_a = L_ - 2;
    const float wa = (float)(ta - (double)lo_a);

    double tb = (double)i_b * step;
    if (tb > (double)(L_ - 1)) tb = (double)(L_ - 1);
    int lo_b = (int)tb;
    if (lo_b > L_ - 2) lo_b = L_ - 2;
    const float wb = (float)(tb - (double)lo_b);

    const long long brow = (long long)b * T_;
    const long long base_a = (brow + start + lo_a) * C4 + c4;
    const long long base_b = (brow + start + lo_b) * C4 + c4;

    // --- issue all 4 loads before any use (MLP = 4) ---
    const float4 vlo_a = x[base_a];
    const float4 vhi_a = x[base_a + C4];
    const float4 vlo_b = x[base_b];
    const float4 vhi_b = x[base_b + C4];

    f32x4 oa, ob;
    oa.x = fmaf(wa, vhi_a.x - vlo_a.x, vlo_a.x);
    oa.y = fmaf(wa, vhi_a.y - vlo_a.y, vlo_a.y);
    oa.z = fmaf(wa, vhi_a.z - vlo_a.z, vlo_a.z);
    oa.w = fmaf(wa, vhi_a.w - vlo_a.w, vlo_a.w);

    ob.x = fmaf(wb, vhi_b.x - vlo_b.x, vlo_b.x);
    ob.y = fmaf(wb, vhi_b.y - vlo_b.y, vlo_b.y);
    ob.z = fmaf(wb, vhi_b.z - vlo_b.z, vlo_b.z);
    ob.w = fmaf(wb, vhi_b.w - vlo_b.w, vlo_b.w);

    f32x4* outv = (f32x4*)out;
    __builtin_nontemporal_store(oa, &outv[(brow + i_a) * C4 + c4]);
    __builtin_nontemporal_store(ob, &outv[(brow + i_b) * C4 + c4]);
}

extern "C" void kernel_launch(void* const* d_in, const int* in_sizes, int n_in,
                              void* d_out, int out_size, void* d_ws, size_t ws_size,
                              hipStream_t stream) {
    const float4* x      = (const float4*)d_in[0];
    const int*    starts = (const int*)d_in[1];
    float4*       out    = (float4*)d_out;

    WindowSlice_kernel<<<NBLK, 256, 0, stream>>>(x, starts, out);
}